// Round 8
// baseline (109.283 us; speedup 1.0000x reference)
//
#include <hip/hip_runtime.h>
#include <math.h>

// NLM S=21, 256x256x3, reflect padding. Round 25 = R24 + two targeted cuts:
// 1. Yodd: half-shifted Y copy in LDS (+11232 B, total 74240 <= 81920 -> still
//    2 blocks/CU). Odd-dv interior H reads aligned half2 from Yodd instead of the
//    27-read + ~26-VALU funnel repack. ~13 slots/offset avg (~2.5%).
// 2. s_setprio(1) around Vmath (T5): barrier-free waves have genuine phase
//    diversity (H DS-burst vs V trans+FMA cluster) -> scheduler arbitration pays
//    in this regime (attn +4-7%, m191); cost-free.
// Ledger: R18-R20 TLP x; R21 reg-headroom/prefetch x; R22 dual-stream ~0;
// R23/24 issue-diet -3% => issue-bound-with-bubbles; keep cutting instructions.

#define IMG 256
#define NPIX (IMG * IMG)
#define TILE 32
#define GR 52      // window-grid dim
#define YD 72      // staged Y rows/cols
#define YSTR 78    // Yreg row stride in halves (39 dwords, odd -> full bank spread)
#define HST 56     // hsT t-stride in halves (28 dwords: rows 16B-aligned -> b128 v-reads)
#define NOFF 441
#define NGB 8      // offset groups (grid.y); 8 wave-streams each -> 64 streams
#define NTHR 512

typedef __attribute__((ext_vector_type(4))) _Float16 half4;
typedef __attribute__((ext_vector_type(2))) _Float16 half2_t;
typedef __attribute__((ext_vector_type(2))) __fp16 fp16x2_t;
typedef __attribute__((ext_vector_type(8))) short short8;

#if __has_builtin(__builtin_amdgcn_fdot2)
#define FDOT2(a, b, c) __builtin_amdgcn_fdot2((a), (b), (c), false)
#else
#define FDOT2(a, b, c) ((c) + (float)(a).x * (float)(b).x + (float)(a).y * (float)(b).y)
#endif

#if __has_builtin(__builtin_amdgcn_sqrtf)
#define ASQRT(x) __builtin_amdgcn_sqrtf(x)
#else
#define ASQRT(x) sqrtf(x)
#endif

#if __has_builtin(__builtin_amdgcn_exp2f)
#define AEXP2(x) __builtin_amdgcn_exp2f(x)
#else
#define AEXP2(x) exp2f(x)
#endif

__device__ __forceinline__ half2_t bcast_f16(float w) {
#if __has_builtin(__builtin_amdgcn_cvt_pkrtz)
    union { fp16x2_t f; half2_t h; } u;
    u.f = __builtin_amdgcn_cvt_pkrtz(w, w);
    return u.h;
#else
    _Float16 wh = (_Float16)w;
    half2_t r; r.x = wh; r.y = wh;
    return r;
#endif
}

__device__ __forceinline__ int refl(int t) {
    t = t < 0 ? -t : t;             // valid for t in [-255, 510]
    return t > 255 ? 510 - t : t;
}

template <bool DIRECT>
__global__ __launch_bounds__(NTHR, 2)
void nlm_main(const float* __restrict__ rgb, const float* __restrict__ hptr,
              float4* __restrict__ partials)
{
    __shared__ __align__(16) _Float16 Yreg[YD][YSTR];      // 11232 B
    __shared__ __align__(16) _Float16 Yodd[YD][YSTR];      // 11232 B (Y shifted by 1 col)
    __shared__ __align__(16) _Float16 Creg4[GR][GR][4];    // 21632 B (epilogue scratch too)
    __shared__ __align__(16) _Float16 hsT[8][TILE][HST];   // 28672 B (private per wave)
    __shared__ unsigned char cjTab[21][GR];                //  1092 B
    // total 73860 B -> 74240 alloc -> 2 blocks/CU (15 KB slack; NOT an exact fit)

    const int tid = threadIdx.x;
    const int tj = ((int)blockIdx.x & 7) * TILE;
    const int ti = ((int)blockIdx.x >> 3) * TILE;

    const int Ybi = min(max(ti - 20, 0), IMG - YD);
    const int Ybj = min(max(tj - 20, 0), IMG - YD);
    const bool interior = (ti >= 20) && (ti + 51 <= 255) && (tj >= 20) && (tj + 51 <= 255);

    // ---- stage Y (clipped luminance, fp16) + half-shifted copy ----
    for (int idx = tid; idx < YD * YD; idx += NTHR) {
        int a = idx / YD, b = idx - a * YD;
        int g = (Ybi + a) * IMG + (Ybj + b);
        float r  = fminf(fmaxf(rgb[g], 0.f), 1.f);
        float gg = fminf(fmaxf(rgb[NPIX + g], 0.f), 1.f);
        float bb = fminf(fmaxf(rgb[2 * NPIX + g], 0.f), 1.f);
        _Float16 yv = (_Float16)(0.299f * r + 0.587f * gg + 0.114f * bb);
        Yreg[a][b] = yv;
        if (b > 0) Yodd[a][b - 1] = yv;        // Yodd[r][c] = Y[r][c+1]
    }
    // ---- stage RGB1 taps at window-grid coords (UNclipped rgb; w-slot = 1) ----
    for (int idx = tid; idx < GR * GR; idx += NTHR) {
        int t = idx / GR, b = idx - t * GR;
        int g = refl(ti - 10 + t) * IMG + refl(tj - 10 + b);
        half4 c;
        c.x = (_Float16)rgb[g];
        c.y = (_Float16)rgb[NPIX + g];
        c.z = (_Float16)rgb[2 * NPIX + g];
        c.w = (_Float16)1.f;                   // weight accumulator partner
        *(half4*)&Creg4[t][b][0] = c;
    }
    // ---- col refl maps for all dv (edge tiles) ----
    if (!interior) {
        for (int idx = tid; idx < 21 * GR; idx += NTHR) {
            int d = idx / GR, c = idx - d * GR;
            cjTab[d][c] = (unsigned char)(refl(refl(tj - 10 + c) + (d - 10)) - Ybj);
        }
    }
    __syncthreads();   // staging complete — last barrier before epilogue

    const int lane = tid & 63;
    const int wv   = tid >> 6;               // wave id 0..7
    const bool hact = lane < GR;

    // ---- persistent y0 row (offset-invariant), 13 VGPRs ----
    half2_t y0h[26];
    if (hact) {
        if (interior) {
            const half2_t* q0 = (const half2_t*)&Yreg[lane + 10][10];
            #pragma unroll
            for (int i = 0; i < 26; ++i) y0h[i] = q0[i];
        } else {
            const _Float16* Y0row = &Yreg[refl(ti - 10 + lane) - Ybi][0];
            const unsigned char* cj0 = &cjTab[10][0];
            #pragma unroll
            for (int i = 0; i < 26; ++i) {
                half2_t v;
                v.x = Y0row[cj0[2 * i]];
                v.y = Y0row[cj0[2 * i + 1]];
                y0h[i] = v;
            }
        }
    }

    const float hv = fmaxf(hptr[0], 0.f);
    // folded: exp(-d/(h+eps)) = exp2(d * negI2), negI2 = -log2(e)/(h+eps)
    const float negI2 = -1.4426950408889634f / (hv + 1e-8f);

    // v decomposition: lane -> (col pb, 16-row strip)
    const int pb  = lane & 31;
    const int s16 = (lane >> 5) << 4;        // 0 or 16

    half2_t accRG[16], accBW[16];            // packed fp16 accumulators (32 VGPRs)
    #pragma unroll
    for (int k = 0; k < 16; ++k) {
        accRG[k].x = (_Float16)0.f; accRG[k].y = (_Float16)0.f;
        accBW[k].x = (_Float16)0.f; accBW[k].y = (_Float16)0.f;
    }

    half2_t one; one.x = (_Float16)1.f; one.y = (_Float16)1.f;

    // ===== phase lambdas (split for dual-stream interleave) =====
    auto Hphase = [&](int du, int dv) {
        const int t = lane;
        half2_t ff[26];
        if (interior) {
            // even dv: aligned pairs from Yreg; odd dv: aligned pairs from Yodd
            const half2_t* q1 = ((dv & 1) == 0)
                ? (const half2_t*)&Yreg[t + 10 + du][10 + dv]
                : (const half2_t*)&Yodd[t + 10 + du][9 + dv];
            #pragma unroll
            for (int i = 0; i < 26; ++i) {
                half2_t d2 = y0h[i] - q1[i];
                ff[i] = d2 * d2;
            }
        } else {
            const unsigned int* cw = (const unsigned int*)&cjTab[dv + 10][0];
            const _Float16* Y1row = &Yreg[refl(refl(ti - 10 + t) + du) - Ybi][0];
            #pragma unroll
            for (int i = 0; i < 26; ++i) {
                unsigned int w0 = cw[i >> 1];
                int sh = (i & 1) * 16;
                _Float16 a0 = Y1row[(w0 >> sh) & 0xffu];
                _Float16 a1 = Y1row[(w0 >> (sh + 8)) & 0xffu];
                half2_t yv; yv.x = a0; yv.y = a1;
                half2_t d2 = y0h[i] - yv;
                ff[i] = d2 * d2;
            }
        }
        // two independent seeds: k=0 (f0..f20), k=16 (f16..f36)
        float s0f = 0.f, s1f = 0.f;
        #pragma unroll
        for (int i = 0; i < 10; ++i) s0f = FDOT2(ff[i], one, s0f);
        s0f += (float)ff[10].x;
        #pragma unroll
        for (int i = 8; i < 18; ++i) s1f = FDOT2(ff[i], one, s1f);
        s1f += (float)ff[18].x;
        _Float16 sA = (_Float16)s0f;
        _Float16 sB = (_Float16)s1f;
        hsT[wv][0][t]  = sA;
        hsT[wv][16][t] = sB;
        // two independent 15-step fp16 chains
        #pragma unroll
        for (int k = 1; k < 16; ++k) {
            {
                int ja = 20 + k, jb = k - 1;
                _Float16 fa = (ja & 1) ? ff[ja >> 1].y : ff[ja >> 1].x;
                _Float16 fb = (jb & 1) ? ff[jb >> 1].y : ff[jb >> 1].x;
                sA += (_Float16)(fa - fb);
                hsT[wv][k][t] = sA;
            }
            {
                int ja = 36 + k, jb = 15 + k;
                _Float16 fa = (ja & 1) ? ff[ja >> 1].y : ff[ja >> 1].x;
                _Float16 fb = (jb & 1) ? ff[jb >> 1].y : ff[jb >> 1].x;
                sB += (_Float16)(fa - fb);
                hsT[wv][16 + k][t] = sB;
            }
        }
    };

    // w2 read: 72B contiguous, 16B-aligned (HST=56) -> 5x ds_read_b128
    auto Vread = [&](half2_t (&w2)[18]) {
        const short8* c8 = (const short8*)&hsT[wv][pb][s16];   // 16B-aligned
        short8 r0 = c8[0], r1 = c8[1], r2 = c8[2], r3 = c8[3], r4 = c8[4];
        union { short8 s; half2_t h[4]; } u0, u1, u2, u3, u4;
        u0.s = r0; u1.s = r1; u2.s = r2; u3.s = r3; u4.s = r4;
        #pragma unroll
        for (int i = 0; i < 4; ++i) w2[i]      = u0.h[i];
        #pragma unroll
        for (int i = 0; i < 4; ++i) w2[4 + i]  = u1.h[i];
        #pragma unroll
        for (int i = 0; i < 4; ++i) w2[8 + i]  = u2.h[i];
        #pragma unroll
        for (int i = 0; i < 4; ++i) w2[12 + i] = u3.h[i];
        w2[16] = u4.h[0]; w2[17] = u4.h[1];    // halves 32..35 (36..39 unused)
    };

    auto Vmath = [&](int du, int dv, half2_t (&w2)[18]) {
        __builtin_amdgcn_s_setprio(1);         // prefer this wave's trans+FMA cluster
        float vs0 = 0.f, vs1 = 0.f;
        #pragma unroll
        for (int i = 0; i < 10; ++i) vs0 = FDOT2(w2[i], one, vs0);
        vs0 += (float)w2[10].x;
        #pragma unroll
        for (int i = 4; i < 14; ++i) vs1 = FDOT2(w2[i], one, vs1);
        vs1 += (float)w2[14].x;

        float vss[16];
        vss[0] = vs0;
        vss[8] = vs1;
        #pragma unroll
        for (int k = 0; k < 7; ++k) {
            {   // chain A: vss[1..7]
                int ja = 21 + k, jb = k;
                _Float16 fa = (ja & 1) ? w2[ja >> 1].y : w2[ja >> 1].x;
                _Float16 fb = (jb & 1) ? w2[jb >> 1].y : w2[jb >> 1].x;
                vss[k + 1] = vss[k] + (float)(_Float16)(fa - fb);
            }
            {   // chain B: vss[9..15]
                int ja = 29 + k, jb = 8 + k;
                _Float16 fa = (ja & 1) ? w2[ja >> 1].y : w2[ja >> 1].x;
                _Float16 fb = (jb & 1) ? w2[jb >> 1].y : w2[jb >> 1].x;
                vss[k + 9] = vss[k + 8] + (float)(_Float16)(fa - fb);
            }
        }

        const int cr = s16 + 10 + du;
        const int cc = pb + 10 + dv;
        #pragma unroll
        for (int k = 0; k < 16; ++k) {
            float dist = ASQRT(fmaxf(vss[k], 0.f));
            float w = AEXP2(dist * negI2);
            half2_t w2v = bcast_f16(w);
            const half2_t* cp = (const half2_t*)&Creg4[cr + k][cc][0];
            half2_t cRG = cp[0];         // (R, G)
            half2_t cBW = cp[1];         // (B, 1)
            accRG[k] = w2v * cRG + accRG[k];   // v_pk_fma_f16
            accBW[k] = w2v * cBW + accBW[k];
        }
        __builtin_amdgcn_s_setprio(0);
    };

    // ---- barrier-free dual-stream offset loop ----
    // stream A: o0 + 128m;  stream B: o0+64 + 128m;  same global order as R17.
    const int o0 = (int)blockIdx.y * 8 + wv;
    int duA = o0 / 21 - 10,       dvA = o0 % 21 - 10;
    int duB = (o0 + 64) / 21 - 10, dvB = (o0 + 64) % 21 - 10;
    half2_t w2A[18], w2B[18];

    #pragma unroll 1
    for (int m = 0; m < 3; ++m) {
        if (hact) Hphase(duA, dvA);    // write strip
        Vread(w2A);                    // read strip (pre-B data; in-order DS)
        if (hact) Hphase(duB, dvB);    // overwrite strip; covers w2A latency
        Vmath(duA, dvA, w2A);          // covers H(B)write -> Vread(B) gap
        Vread(w2B);
        Vmath(duB, dvB, w2B);
        duA += 6; dvA += 2; if (dvA > 10) { dvA -= 21; duA += 1; }
        duB += 6; dvB += 2; if (dvB > 10) { dvB -= 21; duB += 1; }
    }
    // tail: offset o0+384 (valid iff o0 < 57); per-wave divergence is fine (no barriers)
    if (o0 + 384 < NOFF) {
        if (hact) Hphase(duA, dvA);
        Vread(w2A);
        Vmath(duA, dvA, w2A);
    }

    // ---- epilogue: merge 8 wave-streams via reused Creg LDS ----
    __syncthreads();                          // all taps consumed; Creg4 reusable
    float4* scratch = (float4*)&Creg4[0][0][0];   // 1024 x float4 = 16384 B
    #pragma unroll
    for (int w = 0; w < 8; ++w) {
        if (wv == w) {
            #pragma unroll
            for (int k = 0; k < 16; ++k) {
                int px = (s16 + k) * 32 + pb;
                float4 v = make_float4((float)accRG[k].x, (float)accRG[k].y,
                                       (float)accBW[k].x, (float)accBW[k].y);
                if (w == 0) scratch[px] = v;
                else {
                    float4 a = scratch[px];
                    scratch[px] = make_float4(a.x + v.x, a.y + v.y, a.z + v.z, a.w + v.w);
                }
            }
        }
        __syncthreads();
    }
    // ---- store: one float4 per pixel, coalesced ----
    for (int i = tid; i < TILE * TILE; i += NTHR) {
        float4 v = scratch[i];
        int gpix = (ti + (i >> 5)) * IMG + (tj + (i & 31));
        if (DIRECT) {
            partials[(size_t)blockIdx.y * NPIX + gpix] = v;
        } else {
            float* p = (float*)&partials[gpix];
            atomicAdd(p + 0, v.x);
            atomicAdd(p + 1, v.y);
            atomicAdd(p + 2, v.z);
            atomicAdd(p + 3, v.w);
        }
    }
}

template <int NGT>
__global__ __launch_bounds__(256)
void nlm_finalize(const float4* __restrict__ partials, float* __restrict__ out)
{
    int idx = blockIdx.x * blockDim.x + threadIdx.x;
    float r = 0.f, g = 0.f, b = 0.f, w = 0.f;
    #pragma unroll
    for (int gg = 0; gg < NGT; ++gg) {
        float4 p = partials[(size_t)gg * NPIX + idx];
        r += p.x; g += p.y; b += p.z; w += p.w;
    }
    float inv = 1.0f / w;   // sum(w) >= 1 (self offset contributes exp(0))
    out[idx]            = fminf(fmaxf(r * inv, 0.f), 1.f);
    out[NPIX + idx]     = fminf(fmaxf(g * inv, 0.f), 1.f);
    out[2 * NPIX + idx] = fminf(fmaxf(b * inv, 0.f), 1.f);
}

extern "C" void kernel_launch(void* const* d_in, const int* in_sizes, int n_in,
                              void* d_out, int out_size, void* d_ws, size_t ws_size,
                              hipStream_t stream) {
    (void)in_sizes; (void)n_in; (void)out_size;
    const float* rgb  = (const float*)d_in[0];
    const float* hptr = (const float*)d_in[1];
    float* out = (float*)d_out;
    float4* partials = (float4*)d_ws;

    const bool direct = ws_size >= (size_t)NGB * NPIX * sizeof(float4);  // 8.4 MB
    dim3 grid(64, NGB);   // 512 blocks = exactly 2 blocks/CU
    if (direct) {
        nlm_main<true><<<grid, NTHR, 0, stream>>>(rgb, hptr, partials);
        nlm_finalize<NGB><<<NPIX / 256, 256, 0, stream>>>(partials, out);
    } else {
        (void)hipMemsetAsync(partials, 0, (size_t)NPIX * sizeof(float4), stream);
        nlm_main<false><<<grid, NTHR, 0, stream>>>(rgb, hptr, partials);
        nlm_finalize<1><<<NPIX / 256, 256, 0, stream>>>(partials, out);
    }
}

// Round 9
// 98.700 us; speedup vs baseline: 1.1072x; 1.1072x over previous
//
#include <hip/hip_runtime.h>
#include <math.h>

// NLM S=21, 256x256x3, reflect padding. Round 26 = R24 champion + setprio ONLY.
// - R25 post-mortem: LDS 74240 -> occupancy halved (17.9%). Boundary between 63KB
//   (2 blocks) and 74KB (1 block) => usable LDS/CU for co-residency ~128 KiB, not
//   160. Every occupancy experiment was silently capped at 4 waves/SIMD. Solo-block
//   timing (28.7us) vs co-resident (45.6us) => co-residency scaling only 1.26x;
//   VALUBusy 40%@2w -> 50%@4w/SIMD: waves interfere on a shared serial resource.
// - R26: single unconfounded change vs R24: s_setprio(1) around Vmath (T5 regime:
//   barrier-free phase-staggered waves -> scheduler arbitration has role diversity).
// - Everything else byte-identical to R24: dual-offset pipeline, HST=56 b128 vreads,
//   exp2 fold, cvt_pkrtz, 512-thr, 8 waves, 2 blocks/CU, direct-store + finalize.

#define IMG 256
#define NPIX (IMG * IMG)
#define TILE 32
#define GR 52      // window-grid dim
#define YD 72      // staged Y rows/cols
#define YSTR 78    // Yreg row stride in halves (39 dwords, odd -> full bank spread)
#define HST 56     // hsT t-stride in halves (28 dwords: rows 16B-aligned -> b128 v-reads)
#define NOFF 441
#define NGB 8      // offset groups (grid.y); 8 wave-streams each -> 64 streams
#define NTHR 512

typedef __attribute__((ext_vector_type(4))) _Float16 half4;
typedef __attribute__((ext_vector_type(2))) _Float16 half2_t;
typedef __attribute__((ext_vector_type(2))) __fp16 fp16x2_t;
typedef __attribute__((ext_vector_type(8))) short short8;

#if __has_builtin(__builtin_amdgcn_fdot2)
#define FDOT2(a, b, c) __builtin_amdgcn_fdot2((a), (b), (c), false)
#else
#define FDOT2(a, b, c) ((c) + (float)(a).x * (float)(b).x + (float)(a).y * (float)(b).y)
#endif

#if __has_builtin(__builtin_amdgcn_sqrtf)
#define ASQRT(x) __builtin_amdgcn_sqrtf(x)
#else
#define ASQRT(x) sqrtf(x)
#endif

#if __has_builtin(__builtin_amdgcn_exp2f)
#define AEXP2(x) __builtin_amdgcn_exp2f(x)
#else
#define AEXP2(x) exp2f(x)
#endif

__device__ __forceinline__ half2_t bcast_f16(float w) {
#if __has_builtin(__builtin_amdgcn_cvt_pkrtz)
    union { fp16x2_t f; half2_t h; } u;
    u.f = __builtin_amdgcn_cvt_pkrtz(w, w);
    return u.h;
#else
    _Float16 wh = (_Float16)w;
    half2_t r; r.x = wh; r.y = wh;
    return r;
#endif
}

__device__ __forceinline__ int refl(int t) {
    t = t < 0 ? -t : t;             // valid for t in [-255, 510]
    return t > 255 ? 510 - t : t;
}

template <bool DIRECT>
__global__ __launch_bounds__(NTHR, 2)
void nlm_main(const float* __restrict__ rgb, const float* __restrict__ hptr,
              float4* __restrict__ partials)
{
    __shared__ __align__(16) _Float16 Yreg[YD][YSTR];      // 11232 B
    __shared__ __align__(16) _Float16 Creg4[GR][GR][4];    // 21632 B (epilogue scratch too)
    __shared__ __align__(16) _Float16 hsT[8][TILE][HST];   // 28672 B (private per wave)
    __shared__ unsigned char cjTab[21][GR];                //  1092 B
    // total 62628 B -> 62976 alloc -> 2 blocks/CU (16 waves/CU = 4 waves/SIMD;
    // usable-LDS wall is ~128 KiB/CU per R25, so this is the max residency)

    const int tid = threadIdx.x;
    const int tj = ((int)blockIdx.x & 7) * TILE;
    const int ti = ((int)blockIdx.x >> 3) * TILE;

    const int Ybi = min(max(ti - 20, 0), IMG - YD);
    const int Ybj = min(max(tj - 20, 0), IMG - YD);
    const bool interior = (ti >= 20) && (ti + 51 <= 255) && (tj >= 20) && (tj + 51 <= 255);

    // ---- stage Y (clipped luminance, fp16) ----
    for (int idx = tid; idx < YD * YD; idx += NTHR) {
        int a = idx / YD, b = idx - a * YD;
        int g = (Ybi + a) * IMG + (Ybj + b);
        float r  = fminf(fmaxf(rgb[g], 0.f), 1.f);
        float gg = fminf(fmaxf(rgb[NPIX + g], 0.f), 1.f);
        float bb = fminf(fmaxf(rgb[2 * NPIX + g], 0.f), 1.f);
        Yreg[a][b] = (_Float16)(0.299f * r + 0.587f * gg + 0.114f * bb);
    }
    // ---- stage RGB1 taps at window-grid coords (UNclipped rgb; w-slot = 1) ----
    for (int idx = tid; idx < GR * GR; idx += NTHR) {
        int t = idx / GR, b = idx - t * GR;
        int g = refl(ti - 10 + t) * IMG + refl(tj - 10 + b);
        half4 c;
        c.x = (_Float16)rgb[g];
        c.y = (_Float16)rgb[NPIX + g];
        c.z = (_Float16)rgb[2 * NPIX + g];
        c.w = (_Float16)1.f;                   // weight accumulator partner
        *(half4*)&Creg4[t][b][0] = c;
    }
    // ---- col refl maps for all dv (edge tiles) ----
    if (!interior) {
        for (int idx = tid; idx < 21 * GR; idx += NTHR) {
            int d = idx / GR, c = idx - d * GR;
            cjTab[d][c] = (unsigned char)(refl(refl(tj - 10 + c) + (d - 10)) - Ybj);
        }
    }
    __syncthreads();   // staging complete — last barrier before epilogue

    const int lane = tid & 63;
    const int wv   = tid >> 6;               // wave id 0..7
    const bool hact = lane < GR;

    // ---- persistent y0 row (offset-invariant), 13 VGPRs ----
    half2_t y0h[26];
    if (hact) {
        if (interior) {
            const half2_t* q0 = (const half2_t*)&Yreg[lane + 10][10];
            #pragma unroll
            for (int i = 0; i < 26; ++i) y0h[i] = q0[i];
        } else {
            const _Float16* Y0row = &Yreg[refl(ti - 10 + lane) - Ybi][0];
            const unsigned char* cj0 = &cjTab[10][0];
            #pragma unroll
            for (int i = 0; i < 26; ++i) {
                half2_t v;
                v.x = Y0row[cj0[2 * i]];
                v.y = Y0row[cj0[2 * i + 1]];
                y0h[i] = v;
            }
        }
    }

    const float hv = fmaxf(hptr[0], 0.f);
    // folded: exp(-d/(h+eps)) = exp2(d * negI2), negI2 = -log2(e)/(h+eps)
    const float negI2 = -1.4426950408889634f / (hv + 1e-8f);

    // v decomposition: lane -> (col pb, 16-row strip)
    const int pb  = lane & 31;
    const int s16 = (lane >> 5) << 4;        // 0 or 16

    half2_t accRG[16], accBW[16];            // packed fp16 accumulators (32 VGPRs)
    #pragma unroll
    for (int k = 0; k < 16; ++k) {
        accRG[k].x = (_Float16)0.f; accRG[k].y = (_Float16)0.f;
        accBW[k].x = (_Float16)0.f; accBW[k].y = (_Float16)0.f;
    }

    half2_t one; one.x = (_Float16)1.f; one.y = (_Float16)1.f;

    // ===== phase lambdas (R17 bodies, split for dual-stream interleave) =====
    auto Hphase = [&](int du, int dv) {
        const int t = lane;
        half2_t ff[26];
        if (interior) {
            if ((dv & 1) == 0) {
                const half2_t* q1 = (const half2_t*)&Yreg[t + 10 + du][10 + dv];
                #pragma unroll
                for (int i = 0; i < 26; ++i) {
                    half2_t d2 = y0h[i] - q1[i];
                    ff[i] = d2 * d2;
                }
            } else {
                const half2_t* q1 = (const half2_t*)&Yreg[t + 10 + du][10 + dv - 1];
                half2_t prev = q1[0];
                #pragma unroll
                for (int i = 0; i < 26; ++i) {
                    half2_t cur = q1[i + 1];
                    half2_t b; b.x = prev.y; b.y = cur.x;
                    half2_t d2 = y0h[i] - b;
                    ff[i] = d2 * d2;
                    prev = cur;
                }
            }
        } else {
            const unsigned int* cw = (const unsigned int*)&cjTab[dv + 10][0];
            const _Float16* Y1row = &Yreg[refl(refl(ti - 10 + t) + du) - Ybi][0];
            #pragma unroll
            for (int i = 0; i < 26; ++i) {
                unsigned int w0 = cw[i >> 1];
                int sh = (i & 1) * 16;
                _Float16 a0 = Y1row[(w0 >> sh) & 0xffu];
                _Float16 a1 = Y1row[(w0 >> (sh + 8)) & 0xffu];
                half2_t yv; yv.x = a0; yv.y = a1;
                half2_t d2 = y0h[i] - yv;
                ff[i] = d2 * d2;
            }
        }
        // two independent seeds: k=0 (f0..f20), k=16 (f16..f36)
        float s0f = 0.f, s1f = 0.f;
        #pragma unroll
        for (int i = 0; i < 10; ++i) s0f = FDOT2(ff[i], one, s0f);
        s0f += (float)ff[10].x;
        #pragma unroll
        for (int i = 8; i < 18; ++i) s1f = FDOT2(ff[i], one, s1f);
        s1f += (float)ff[18].x;
        _Float16 sA = (_Float16)s0f;
        _Float16 sB = (_Float16)s1f;
        hsT[wv][0][t]  = sA;
        hsT[wv][16][t] = sB;
        // two independent 15-step fp16 chains
        #pragma unroll
        for (int k = 1; k < 16; ++k) {
            {
                int ja = 20 + k, jb = k - 1;
                _Float16 fa = (ja & 1) ? ff[ja >> 1].y : ff[ja >> 1].x;
                _Float16 fb = (jb & 1) ? ff[jb >> 1].y : ff[jb >> 1].x;
                sA += (_Float16)(fa - fb);
                hsT[wv][k][t] = sA;
            }
            {
                int ja = 36 + k, jb = 15 + k;
                _Float16 fa = (ja & 1) ? ff[ja >> 1].y : ff[ja >> 1].x;
                _Float16 fb = (jb & 1) ? ff[jb >> 1].y : ff[jb >> 1].x;
                sB += (_Float16)(fa - fb);
                hsT[wv][16 + k][t] = sB;
            }
        }
    };

    // w2 read: 72B contiguous, 16B-aligned (HST=56) -> 5x ds_read_b128
    auto Vread = [&](half2_t (&w2)[18]) {
        const short8* c8 = (const short8*)&hsT[wv][pb][s16];   // 16B-aligned
        short8 r0 = c8[0], r1 = c8[1], r2 = c8[2], r3 = c8[3], r4 = c8[4];
        union { short8 s; half2_t h[4]; } u0, u1, u2, u3, u4;
        u0.s = r0; u1.s = r1; u2.s = r2; u3.s = r3; u4.s = r4;
        #pragma unroll
        for (int i = 0; i < 4; ++i) w2[i]      = u0.h[i];
        #pragma unroll
        for (int i = 0; i < 4; ++i) w2[4 + i]  = u1.h[i];
        #pragma unroll
        for (int i = 0; i < 4; ++i) w2[8 + i]  = u2.h[i];
        #pragma unroll
        for (int i = 0; i < 4; ++i) w2[12 + i] = u3.h[i];
        w2[16] = u4.h[0]; w2[17] = u4.h[1];    // halves 32..35 (36..39 unused)
    };

    auto Vmath = [&](int du, int dv, half2_t (&w2)[18]) {
        __builtin_amdgcn_s_setprio(1);         // T5: prefer this wave's trans+FMA cluster
        float vs0 = 0.f, vs1 = 0.f;
        #pragma unroll
        for (int i = 0; i < 10; ++i) vs0 = FDOT2(w2[i], one, vs0);
        vs0 += (float)w2[10].x;
        #pragma unroll
        for (int i = 4; i < 14; ++i) vs1 = FDOT2(w2[i], one, vs1);
        vs1 += (float)w2[14].x;

        float vss[16];
        vss[0] = vs0;
        vss[8] = vs1;
        #pragma unroll
        for (int k = 0; k < 7; ++k) {
            {   // chain A: vss[1..7]
                int ja = 21 + k, jb = k;
                _Float16 fa = (ja & 1) ? w2[ja >> 1].y : w2[ja >> 1].x;
                _Float16 fb = (jb & 1) ? w2[jb >> 1].y : w2[jb >> 1].x;
                vss[k + 1] = vss[k] + (float)(_Float16)(fa - fb);
            }
            {   // chain B: vss[9..15]
                int ja = 29 + k, jb = 8 + k;
                _Float16 fa = (ja & 1) ? w2[ja >> 1].y : w2[ja >> 1].x;
                _Float16 fb = (jb & 1) ? w2[jb >> 1].y : w2[jb >> 1].x;
                vss[k + 9] = vss[k + 8] + (float)(_Float16)(fa - fb);
            }
        }

        const int cr = s16 + 10 + du;
        const int cc = pb + 10 + dv;
        #pragma unroll
        for (int k = 0; k < 16; ++k) {
            float dist = ASQRT(fmaxf(vss[k], 0.f));
            float w = AEXP2(dist * negI2);
            half2_t w2v = bcast_f16(w);
            const half2_t* cp = (const half2_t*)&Creg4[cr + k][cc][0];
            half2_t cRG = cp[0];         // (R, G)
            half2_t cBW = cp[1];         // (B, 1)
            accRG[k] = w2v * cRG + accRG[k];   // v_pk_fma_f16
            accBW[k] = w2v * cBW + accBW[k];
        }
        __builtin_amdgcn_s_setprio(0);
    };

    // ---- barrier-free dual-stream offset loop ----
    // stream A: o0 + 128m;  stream B: o0+64 + 128m;  same global order as R17.
    const int o0 = (int)blockIdx.y * 8 + wv;
    int duA = o0 / 21 - 10,       dvA = o0 % 21 - 10;
    int duB = (o0 + 64) / 21 - 10, dvB = (o0 + 64) % 21 - 10;
    half2_t w2A[18], w2B[18];

    #pragma unroll 1
    for (int m = 0; m < 3; ++m) {
        if (hact) Hphase(duA, dvA);    // write strip
        Vread(w2A);                    // read strip (pre-B data; in-order DS)
        if (hact) Hphase(duB, dvB);    // overwrite strip; covers w2A latency
        Vmath(duA, dvA, w2A);          // covers H(B)write -> Vread(B) gap
        Vread(w2B);
        Vmath(duB, dvB, w2B);
        duA += 6; dvA += 2; if (dvA > 10) { dvA -= 21; duA += 1; }
        duB += 6; dvB += 2; if (dvB > 10) { dvB -= 21; duB += 1; }
    }
    // tail: offset o0+384 (valid iff o0 < 57); per-wave divergence is fine (no barriers)
    if (o0 + 384 < NOFF) {
        if (hact) Hphase(duA, dvA);
        Vread(w2A);
        Vmath(duA, dvA, w2A);
    }

    // ---- epilogue: merge 8 wave-streams via reused Creg LDS ----
    __syncthreads();                          // all taps consumed; Creg4 reusable
    float4* scratch = (float4*)&Creg4[0][0][0];   // 1024 x float4 = 16384 B
    #pragma unroll
    for (int w = 0; w < 8; ++w) {
        if (wv == w) {
            #pragma unroll
            for (int k = 0; k < 16; ++k) {
                int px = (s16 + k) * 32 + pb;
                float4 v = make_float4((float)accRG[k].x, (float)accRG[k].y,
                                       (float)accBW[k].x, (float)accBW[k].y);
                if (w == 0) scratch[px] = v;
                else {
                    float4 a = scratch[px];
                    scratch[px] = make_float4(a.x + v.x, a.y + v.y, a.z + v.z, a.w + v.w);
                }
            }
        }
        __syncthreads();
    }
    // ---- store: one float4 per pixel, coalesced ----
    for (int i = tid; i < TILE * TILE; i += NTHR) {
        float4 v = scratch[i];
        int gpix = (ti + (i >> 5)) * IMG + (tj + (i & 31));
        if (DIRECT) {
            partials[(size_t)blockIdx.y * NPIX + gpix] = v;
        } else {
            float* p = (float*)&partials[gpix];
            atomicAdd(p + 0, v.x);
            atomicAdd(p + 1, v.y);
            atomicAdd(p + 2, v.z);
            atomicAdd(p + 3, v.w);
        }
    }
}

template <int NGT>
__global__ __launch_bounds__(256)
void nlm_finalize(const float4* __restrict__ partials, float* __restrict__ out)
{
    int idx = blockIdx.x * blockDim.x + threadIdx.x;
    float r = 0.f, g = 0.f, b = 0.f, w = 0.f;
    #pragma unroll
    for (int gg = 0; gg < NGT; ++gg) {
        float4 p = partials[(size_t)gg * NPIX + idx];
        r += p.x; g += p.y; b += p.z; w += p.w;
    }
    float inv = 1.0f / w;   // sum(w) >= 1 (self offset contributes exp(0))
    out[idx]            = fminf(fmaxf(r * inv, 0.f), 1.f);
    out[NPIX + idx]     = fminf(fmaxf(g * inv, 0.f), 1.f);
    out[2 * NPIX + idx] = fminf(fmaxf(b * inv, 0.f), 1.f);
}

extern "C" void kernel_launch(void* const* d_in, const int* in_sizes, int n_in,
                              void* d_out, int out_size, void* d_ws, size_t ws_size,
                              hipStream_t stream) {
    (void)in_sizes; (void)n_in; (void)out_size;
    const float* rgb  = (const float*)d_in[0];
    const float* hptr = (const float*)d_in[1];
    float* out = (float*)d_out;
    float4* partials = (float4*)d_ws;

    const bool direct = ws_size >= (size_t)NGB * NPIX * sizeof(float4);  // 8.4 MB
    dim3 grid(64, NGB);   // 512 blocks = exactly 2 blocks/CU
    if (direct) {
        nlm_main<true><<<grid, NTHR, 0, stream>>>(rgb, hptr, partials);
        nlm_finalize<NGB><<<NPIX / 256, 256, 0, stream>>>(partials, out);
    } else {
        (void)hipMemsetAsync(partials, 0, (size_t)NPIX * sizeof(float4), stream);
        nlm_main<false><<<grid, NTHR, 0, stream>>>(rgb, hptr, partials);
        nlm_finalize<1><<<NPIX / 256, 256, 0, stream>>>(partials, out);
    }
}